// Round 5
// baseline (520.247 us; speedup 1.0000x reference)
//
#include <hip/hip_runtime.h>

#define FEAT 256
#define SEQ  2048
#define NBATCH 16

typedef float  f32x4  __attribute__((ext_vector_type(4)));
typedef __bf16 bf16x8 __attribute__((ext_vector_type(8)));

__device__ __forceinline__ unsigned short f2bf(float f) {
  union { float f; unsigned int u; } v; v.f = f;
  unsigned int r = (v.u + 0x7fffu + ((v.u >> 16) & 1u)) >> 16;
  return (unsigned short)r;
}

__device__ __forceinline__ float redsum16(float t) {
  t += __shfl_xor(t, 1);
  t += __shfl_xor(t, 2);
  t += __shfl_xor(t, 4);
  t += __shfl_xor(t, 8);
  return t;
}

// ---------------- kernel 0: convert weights fp32 -> bf16 ----------------
__global__ __launch_bounds__(256) void k_wcvt(
    const float* __restrict__ Wq, const float* __restrict__ Wk,
    const float* __restrict__ Wv, const float* __restrict__ W2,
    unsigned short* __restrict__ Wqb, unsigned short* __restrict__ Wkb,
    unsigned short* __restrict__ Wvb, unsigned short* __restrict__ W2b) {
  int i = blockIdx.x * 256 + threadIdx.x;  // 65536 total
  Wqb[i] = f2bf(Wq[i]);
  Wkb[i] = f2bf(Wk[i]);
  Wvb[i] = f2bf(Wv[i]);
  W2b[i] = f2bf(W2[i]);
}

// ---------------- kernel 1: h = x + posenc(p), bf16 out ----------------
__global__ __launch_bounds__(256) void k_pos_h(
    const float* __restrict__ x, const float* __restrict__ p,
    const float* __restrict__ W1, const float* __restrict__ b1,
    const unsigned short* __restrict__ W2b, const float* __restrict__ b2,
    unsigned short* __restrict__ hb) {
  __shared__ __align__(16) unsigned short tlds[64 * 264];
  __shared__ float pl[192];
  const int tid = threadIdx.x;
  const int blk = blockIdx.x;
  const int tok0 = blk * 64;
  if (tid < 192) pl[tid] = p[tok0 * 3 + tid];
  __syncthreads();
  // phase A: t = relu(p @ W1^T + b1), thread owns feature j = tid
  const int j = tid;
  const float w0 = W1[j * 3 + 0], w1 = W1[j * 3 + 1], w2 = W1[j * 3 + 2];
  const float bb = b1[j];
#pragma unroll 4
  for (int tl = 0; tl < 64; ++tl) {
    float v = bb + pl[tl * 3 + 0] * w0 + pl[tl * 3 + 1] * w1 + pl[tl * 3 + 2] * w2;
    v = v > 0.f ? v : 0.f;
    tlds[tl * 264 + j] = f2bf(v);
  }
  __syncthreads();
  // phase B: pos = t @ W2^T ; h = x + pos + b2
  const int w = tid >> 6, lane = tid & 63;
  const int col = lane & 15, quad = lane >> 4;
  bf16x8 af[8];
  const unsigned short* arow = tlds + (w * 16 + col) * 264 + quad * 8;
#pragma unroll
  for (int ks = 0; ks < 8; ++ks) af[ks] = *(const bf16x8*)(arow + ks * 32);
#pragma unroll 1
  for (int ct = 0; ct < 16; ++ct) {
    f32x4 acc = {0.f, 0.f, 0.f, 0.f};
    const unsigned short* brow = W2b + (ct * 16 + col) * 256 + quad * 8;
#pragma unroll
    for (int ks = 0; ks < 8; ++ks) {
      bf16x8 bf = *(const bf16x8*)(brow + ks * 32);
      acc = __builtin_amdgcn_mfma_f32_16x16x32_bf16(af[ks], bf, acc, 0, 0, 0);
    }
    const int f = ct * 16 + col;
    const float bias = b2[f];
#pragma unroll
    for (int r = 0; r < 4; ++r) {
      const int tok = tok0 + w * 16 + quad * 4 + r;
      float v = acc[r] + bias + x[tok * 256 + f];
      hb[tok * 256 + f] = f2bf(v);
    }
  }
}

// ---------------- kernel 2: q,k,v projections (note reference name swap!) ----
// q = h @ Wk^T + bk ; k = h @ Wq^T + bq ; v = h @ Wv^T + bv.
// 128 tokens/block, 32/wave as 2 row-frags: each B-fragment load from L2 feeds
// 2 MFMAs (weight L2 traffic halved vs 16 rows/wave).
__global__ __launch_bounds__(256) void k_qkv(
    const unsigned short* __restrict__ hb,
    const unsigned short* __restrict__ Wqb, const float* __restrict__ bq,
    const unsigned short* __restrict__ Wkb, const float* __restrict__ bk,
    const unsigned short* __restrict__ Wvb, const float* __restrict__ bv,
    unsigned short* __restrict__ qb, unsigned short* __restrict__ kb,
    unsigned short* __restrict__ vtb) {
  const int tid = threadIdx.x, blk = blockIdx.x;
  const int w = tid >> 6, lane = tid & 63;
  const int col = lane & 15, quad = lane >> 4;
  const int row0 = blk * 128 + w * 32;
  bf16x8 af0[8], af1[8];
  const unsigned short* arow0 = hb + (size_t)(row0 + col) * 256 + quad * 8;
  const unsigned short* arow1 = arow0 + 16 * 256;
#pragma unroll
  for (int ks = 0; ks < 8; ++ks) {
    af0[ks] = *(const bf16x8*)(arow0 + ks * 32);
    af1[ks] = *(const bf16x8*)(arow1 + ks * 32);
  }
#pragma unroll 1
  for (int mat = 0; mat < 3; ++mat) {
    const unsigned short* W = (mat == 0) ? Wkb : ((mat == 1) ? Wqb : Wvb);
    const float* bias = (mat == 0) ? bk : ((mat == 1) ? bq : bv);
#pragma unroll 1
    for (int ct = 0; ct < 16; ++ct) {
      f32x4 a0 = {0.f, 0.f, 0.f, 0.f}, a1 = {0.f, 0.f, 0.f, 0.f};
      const unsigned short* brow = W + (ct * 16 + col) * 256 + quad * 8;
#pragma unroll
      for (int ks = 0; ks < 8; ++ks) {
        bf16x8 bf = *(const bf16x8*)(brow + ks * 32);
        a0 = __builtin_amdgcn_mfma_f32_16x16x32_bf16(af0[ks], bf, a0, 0, 0, 0);
        a1 = __builtin_amdgcn_mfma_f32_16x16x32_bf16(af1[ks], bf, a1, 0, 0, 0);
      }
      const int f = ct * 16 + col;
      const float bs = bias[f];
      if (mat < 2) {
        unsigned short* dst = (mat == 0) ? qb : kb;
#pragma unroll
        for (int r = 0; r < 4; ++r) {
          dst[(size_t)(row0 + quad * 4 + r) * 256 + f] = f2bf(a0[r] + bs);
          dst[(size_t)(row0 + 16 + quad * 4 + r) * 256 + f] = f2bf(a1[r] + bs);
        }
      } else {
        ushort4 pk0, pk1;
        pk0.x = f2bf(a0[0] + bs); pk0.y = f2bf(a0[1] + bs);
        pk0.z = f2bf(a0[2] + bs); pk0.w = f2bf(a0[3] + bs);
        pk1.x = f2bf(a1[0] + bs); pk1.y = f2bf(a1[1] + bs);
        pk1.z = f2bf(a1[2] + bs); pk1.w = f2bf(a1[3] + bs);
        const int t0 = row0 + quad * 4;
        const int b0 = t0 >> 11, n0 = t0 & 2047;
        *(ushort4*)(vtb + (size_t)(b0 * 256 + f) * 2048 + n0) = pk0;
        const int t1 = t0 + 16;
        const int b1_ = t1 >> 11, n1 = t1 & 2047;
        *(ushort4*)(vtb + (size_t)(b1_ * 256 + f) * 2048 + n1) = pk1;
      }
    }
  }
}

// ---------------- kernel 3: flash attention ----------------
// Round-4 model: LDS-BW-bound (528 b128-reads/CU-iter x 8cyc = 4.2K cyc matched
// 139us wall). Fix: 32 q-rows/wave (2 row-frags) -> each K/V LDS read feeds 2
// MFMAs. Block = 4 waves x 32 rows = 128 q-rows, grid (16,16) = 1 block/CU.
// Global->register prefetch: tile kt+1 loads issued before compute of kt, so
// the vmcnt wait (at the LDS writes) lands after a full compute phase.
// Fixed-offset softmax (exp(s*scale-8), pure-sum O and l) per round 4.
// Epilogue fully unrolled (dynamic O index -> scratch demotion, rounds 1-2).
// LDS 42.5 KB static. WRITE_SIZE tripwire: >100MB means spill -> revert LB.
__global__ __launch_bounds__(256, 1) void k_attn(
    const unsigned short* __restrict__ qb, const unsigned short* __restrict__ kb,
    const unsigned short* __restrict__ vtb, float* __restrict__ out) {
  __shared__ __align__(16) unsigned short Kl[32 * 264];    // [key][f], pad 264
  __shared__ __align__(16) unsigned short Vt[256 * 32];    // [f][key], no pad
  __shared__ __align__(16) unsigned short Pl[4][32 * 36];  // [wave][row][key] pad 36
  const int tid = threadIdx.x;
  const int bx = blockIdx.x, b = blockIdx.y;
  const int w = tid >> 6, lane = tid & 63;
  const int col = lane & 15, quad = lane >> 4;
  const int n0 = bx * 128 + w * 32;
  const float scale = 0.0625f;  // 1/sqrt(256)

  // q A-frags for 2 row-tiles (64 VGPRs)
  bf16x8 qf0[8], qf1[8];
  const unsigned short* qrow0 = qb + (size_t)(b * 2048 + n0 + col) * 256 + quad * 8;
  const unsigned short* qrow1 = qrow0 + 16 * 256;
#pragma unroll
  for (int ks = 0; ks < 8; ++ks) {
    qf0[ks] = *(const bf16x8*)(qrow0 + ks * 32);
    qf1[ks] = *(const bf16x8*)(qrow1 + ks * 32);
  }

  f32x4 O0[16], O1[16];
#pragma unroll
  for (int ft = 0; ft < 16; ++ft) {
    O0[ft] = (f32x4){0.f, 0.f, 0.f, 0.f};
    O1[ft] = (f32x4){0.f, 0.f, 0.f, 0.f};
  }
  float ls0[4], ls1[4];
#pragma unroll
  for (int r = 0; r < 4; ++r) { ls0[r] = 0.f; ls1[r] = 0.f; }

  const uint4* ksrc = (const uint4*)(kb) + (size_t)b * 2048 * 32;  // [row][c:32]
  const uint4* vsrc = (const uint4*)(vtb);  // [(b*256+f)*256 + kt*4 + c]

  uint4 pk[4], pv[4];
  // prefetch tile 0
#pragma unroll
  for (int pp = 0; pp < 4; ++pp) {
    const int idx = pp * 256 + tid;
    const int r = idx >> 5, c = idx & 31;
    pk[pp] = ksrc[(size_t)r * 32 + c];
    const int f = idx >> 2, cc = idx & 3;
    pv[pp] = vsrc[(size_t)(b * 256 + f) * 256 + cc];
  }

  unsigned short* Pw = Pl[w];

  for (int kt = 0; kt < 64; ++kt) {
    __syncthreads();  // all waves done reading K/V LDS of prev iter
    // write prefetched tile kt into LDS (vmcnt wait lands here)
#pragma unroll
    for (int pp = 0; pp < 4; ++pp) {
      const int idx = pp * 256 + tid;
      const int r = idx >> 5, c = idx & 31;
      *(uint4*)(Kl + r * 264 + c * 8) = pk[pp];
      const int f = idx >> 2, cc = idx & 3;
      *(uint4*)(Vt + f * 32 + cc * 8) = pv[pp];
    }
    // issue loads for tile kt+1 (in flight during compute below)
    if (kt + 1 < 64) {
#pragma unroll
      for (int pp = 0; pp < 4; ++pp) {
        const int idx = pp * 256 + tid;
        const int r = idx >> 5, c = idx & 31;
        pk[pp] = ksrc[(size_t)((kt + 1) * 32 + r) * 32 + c];
        const int f = idx >> 2, cc = idx & 3;
        pv[pp] = vsrc[(size_t)(b * 256 + f) * 256 + (kt + 1) * 4 + cc];
      }
    }
    __syncthreads();  // LDS tile ready
    // S = q @ k^T : 2 row-frags x 2 key-tiles; K-frags shared across row-frags
    f32x4 s00 = {0.f, 0.f, 0.f, 0.f}, s01 = {0.f, 0.f, 0.f, 0.f};
    f32x4 s10 = {0.f, 0.f, 0.f, 0.f}, s11 = {0.f, 0.f, 0.f, 0.f};
#pragma unroll
    for (int ks = 0; ks < 8; ++ks) {
      bf16x8 k0 = *(const bf16x8*)(Kl + col * 264 + ks * 32 + quad * 8);
      bf16x8 k1 = *(const bf16x8*)(Kl + (16 + col) * 264 + ks * 32 + quad * 8);
      s00 = __builtin_amdgcn_mfma_f32_16x16x32_bf16(qf0[ks], k0, s00, 0, 0, 0);
      s01 = __builtin_amdgcn_mfma_f32_16x16x32_bf16(qf0[ks], k1, s01, 0, 0, 0);
      s10 = __builtin_amdgcn_mfma_f32_16x16x32_bf16(qf1[ks], k0, s10, 0, 0, 0);
      s11 = __builtin_amdgcn_mfma_f32_16x16x32_bf16(qf1[ks], k1, s11, 0, 0, 0);
    }
    // fixed-offset exp; lane-local l accumulation; P -> per-wave LDS
#pragma unroll
    for (int r = 0; r < 4; ++r) {
      float p0 = __expf(fmaf(s00[r], scale, -8.0f));
      float p1 = __expf(fmaf(s01[r], scale, -8.0f));
      ls0[r] += p0 + p1;
      Pw[(quad * 4 + r) * 36 + col] = f2bf(p0);
      Pw[(quad * 4 + r) * 36 + 16 + col] = f2bf(p1);
      float q0 = __expf(fmaf(s10[r], scale, -8.0f));
      float q1 = __expf(fmaf(s11[r], scale, -8.0f));
      ls1[r] += q0 + q1;
      Pw[(16 + quad * 4 + r) * 36 + col] = f2bf(q0);
      Pw[(16 + quad * 4 + r) * 36 + 16 + col] = f2bf(q1);
    }
    // NO barrier: Pl[w] is per-wave; same-wave LDS RAW ordered by lgkmcnt.
    bf16x8 pf0 = *(const bf16x8*)(Pw + col * 36 + quad * 8);
    bf16x8 pf1 = *(const bf16x8*)(Pw + (16 + col) * 36 + quad * 8);
    // PV: O += P @ V ; V-frags shared across row-frags
#pragma unroll
    for (int ft = 0; ft < 16; ++ft) {
      bf16x8 vf = *(const bf16x8*)(Vt + (ft * 16 + col) * 32 + quad * 8);
      O0[ft] = __builtin_amdgcn_mfma_f32_16x16x32_bf16(pf0, vf, O0[ft], 0, 0, 0);
      O1[ft] = __builtin_amdgcn_mfma_f32_16x16x32_bf16(pf1, vf, O1[ft], 0, 0, 0);
    }
  }
  // epilogue: out = O / l  (FULLY UNROLLED — all O indices must be static)
  float rl0[4], rl1[4];
#pragma unroll
  for (int r = 0; r < 4; ++r) {
    rl0[r] = 1.0f / redsum16(ls0[r]);
    rl1[r] = 1.0f / redsum16(ls1[r]);
  }
#pragma unroll
  for (int ft = 0; ft < 16; ++ft) {
#pragma unroll
    for (int r = 0; r < 4; ++r) {
      const int n = n0 + quad * 4 + r;
      out[(size_t)(b * 2048 + n) * 256 + ft * 16 + col] = O0[ft][r] * rl0[r];
      out[(size_t)(b * 2048 + n + 16) * 256 + ft * 16 + col] = O1[ft][r] * rl1[r];
    }
  }
}

// ---------------- launcher ----------------
extern "C" void kernel_launch(void* const* d_in, const int* in_sizes, int n_in,
                              void* d_out, int out_size, void* d_ws, size_t ws_size,
                              hipStream_t stream) {
  const float* x  = (const float*)d_in[0];
  const float* p  = (const float*)d_in[1];
  const float* Wq = (const float*)d_in[2];
  const float* bq = (const float*)d_in[3];
  const float* Wk = (const float*)d_in[4];
  const float* bk = (const float*)d_in[5];
  const float* Wv = (const float*)d_in[6];
  const float* bv = (const float*)d_in[7];
  const float* W1 = (const float*)d_in[8];
  const float* b1 = (const float*)d_in[9];
  const float* W2 = (const float*)d_in[10];
  const float* b2 = (const float*)d_in[11];
  float* out = (float*)d_out;

  char* ws = (char*)d_ws;
  unsigned short* W2b = (unsigned short*)(ws + 0);
  unsigned short* Wqb = (unsigned short*)(ws + 131072);
  unsigned short* Wkb = (unsigned short*)(ws + 262144);
  unsigned short* Wvb = (unsigned short*)(ws + 393216);
  unsigned short* hb  = (unsigned short*)(ws + 524288);
  unsigned short* qb  = (unsigned short*)(ws + 524288 + 16777216);
  unsigned short* kb  = (unsigned short*)(ws + 524288 + 2 * 16777216);
  unsigned short* vtb = (unsigned short*)(ws + 524288 + 3 * 16777216);
  // total ws use: 524288 + 4*16777216 = 67,633,152 bytes

  k_wcvt<<<256, 256, 0, stream>>>(Wq, Wk, Wv, W2, Wqb, Wkb, Wvb, W2b);
  k_pos_h<<<512, 256, 0, stream>>>(x, p, W1, b1, W2b, b2, hb);
  k_qkv<<<256, 256, 0, stream>>>(hb, Wqb, bq, Wkb, bk, Wvb, bv, qb, kb, vtb);
  k_attn<<<dim3(16, 16), 256, 0, stream>>>(qb, kb, vtb, out);
}

// Round 6
// 340.362 us; speedup vs baseline: 1.5285x; 1.5285x over previous
//
#include <hip/hip_runtime.h>

#define FEAT 256
#define SEQ  2048
#define NBATCH 16

typedef float  f32x4  __attribute__((ext_vector_type(4)));
typedef __bf16 bf16x8 __attribute__((ext_vector_type(8)));

__device__ __forceinline__ unsigned short f2bf(float f) {
  union { float f; unsigned int u; } v; v.f = f;
  unsigned int r = (v.u + 0x7fffu + ((v.u >> 16) & 1u)) >> 16;
  return (unsigned short)r;
}

__device__ __forceinline__ float redsum16(float t) {
  t += __shfl_xor(t, 1);
  t += __shfl_xor(t, 2);
  t += __shfl_xor(t, 4);
  t += __shfl_xor(t, 8);
  return t;
}

// ---------------- kernel 0: convert weights fp32 -> bf16 ----------------
__global__ __launch_bounds__(256) void k_wcvt(
    const float* __restrict__ Wq, const float* __restrict__ Wk,
    const float* __restrict__ Wv, const float* __restrict__ W2,
    unsigned short* __restrict__ Wqb, unsigned short* __restrict__ Wkb,
    unsigned short* __restrict__ Wvb, unsigned short* __restrict__ W2b) {
  int i = blockIdx.x * 256 + threadIdx.x;  // 65536 total
  Wqb[i] = f2bf(Wq[i]);
  Wkb[i] = f2bf(Wk[i]);
  Wvb[i] = f2bf(Wv[i]);
  W2b[i] = f2bf(W2[i]);
}

// ---------------- kernel 1: h = x + posenc(p), bf16 out ----------------
__global__ __launch_bounds__(256) void k_pos_h(
    const float* __restrict__ x, const float* __restrict__ p,
    const float* __restrict__ W1, const float* __restrict__ b1,
    const unsigned short* __restrict__ W2b, const float* __restrict__ b2,
    unsigned short* __restrict__ hb) {
  __shared__ __align__(16) unsigned short tlds[64 * 264];
  __shared__ float pl[192];
  const int tid = threadIdx.x;
  const int blk = blockIdx.x;
  const int tok0 = blk * 64;
  if (tid < 192) pl[tid] = p[tok0 * 3 + tid];
  __syncthreads();
  // phase A: t = relu(p @ W1^T + b1), thread owns feature j = tid
  const int j = tid;
  const float w0 = W1[j * 3 + 0], w1 = W1[j * 3 + 1], w2 = W1[j * 3 + 2];
  const float bb = b1[j];
#pragma unroll 4
  for (int tl = 0; tl < 64; ++tl) {
    float v = bb + pl[tl * 3 + 0] * w0 + pl[tl * 3 + 1] * w1 + pl[tl * 3 + 2] * w2;
    v = v > 0.f ? v : 0.f;
    tlds[tl * 264 + j] = f2bf(v);
  }
  __syncthreads();
  // phase B: pos = t @ W2^T ; h = x + pos + b2
  const int w = tid >> 6, lane = tid & 63;
  const int col = lane & 15, quad = lane >> 4;
  bf16x8 af[8];
  const unsigned short* arow = tlds + (w * 16 + col) * 264 + quad * 8;
#pragma unroll
  for (int ks = 0; ks < 8; ++ks) af[ks] = *(const bf16x8*)(arow + ks * 32);
#pragma unroll 1
  for (int ct = 0; ct < 16; ++ct) {
    f32x4 acc = {0.f, 0.f, 0.f, 0.f};
    const unsigned short* brow = W2b + (ct * 16 + col) * 256 + quad * 8;
#pragma unroll
    for (int ks = 0; ks < 8; ++ks) {
      bf16x8 bf = *(const bf16x8*)(brow + ks * 32);
      acc = __builtin_amdgcn_mfma_f32_16x16x32_bf16(af[ks], bf, acc, 0, 0, 0);
    }
    const int f = ct * 16 + col;
    const float bias = b2[f];
#pragma unroll
    for (int r = 0; r < 4; ++r) {
      const int tok = tok0 + w * 16 + quad * 4 + r;
      float v = acc[r] + bias + x[tok * 256 + f];
      hb[tok * 256 + f] = f2bf(v);
    }
  }
}

// ---------------- kernel 2: q,k,v projections (note reference name swap!) ----
// q = h @ Wk^T + bk ; k = h @ Wq^T + bq ; v = h @ Wv^T + bv.
// 128 tokens/block, 32/wave as 2 row-frags: each B-fragment load from L2 feeds
// 2 MFMAs.
__global__ __launch_bounds__(256) void k_qkv(
    const unsigned short* __restrict__ hb,
    const unsigned short* __restrict__ Wqb, const float* __restrict__ bq,
    const unsigned short* __restrict__ Wkb, const float* __restrict__ bk,
    const unsigned short* __restrict__ Wvb, const float* __restrict__ bv,
    unsigned short* __restrict__ qb, unsigned short* __restrict__ kb,
    unsigned short* __restrict__ vtb) {
  const int tid = threadIdx.x, blk = blockIdx.x;
  const int w = tid >> 6, lane = tid & 63;
  const int col = lane & 15, quad = lane >> 4;
  const int row0 = blk * 128 + w * 32;
  bf16x8 af0[8], af1[8];
  const unsigned short* arow0 = hb + (size_t)(row0 + col) * 256 + quad * 8;
  const unsigned short* arow1 = arow0 + 16 * 256;
#pragma unroll
  for (int ks = 0; ks < 8; ++ks) {
    af0[ks] = *(const bf16x8*)(arow0 + ks * 32);
    af1[ks] = *(const bf16x8*)(arow1 + ks * 32);
  }
#pragma unroll 1
  for (int mat = 0; mat < 3; ++mat) {
    const unsigned short* W = (mat == 0) ? Wkb : ((mat == 1) ? Wqb : Wvb);
    const float* bias = (mat == 0) ? bk : ((mat == 1) ? bq : bv);
#pragma unroll 1
    for (int ct = 0; ct < 16; ++ct) {
      f32x4 a0 = {0.f, 0.f, 0.f, 0.f}, a1 = {0.f, 0.f, 0.f, 0.f};
      const unsigned short* brow = W + (ct * 16 + col) * 256 + quad * 8;
#pragma unroll
      for (int ks = 0; ks < 8; ++ks) {
        bf16x8 bf = *(const bf16x8*)(brow + ks * 32);
        a0 = __builtin_amdgcn_mfma_f32_16x16x32_bf16(af0[ks], bf, a0, 0, 0, 0);
        a1 = __builtin_amdgcn_mfma_f32_16x16x32_bf16(af1[ks], bf, a1, 0, 0, 0);
      }
      const int f = ct * 16 + col;
      const float bs = bias[f];
      if (mat < 2) {
        unsigned short* dst = (mat == 0) ? qb : kb;
#pragma unroll
        for (int r = 0; r < 4; ++r) {
          dst[(size_t)(row0 + quad * 4 + r) * 256 + f] = f2bf(a0[r] + bs);
          dst[(size_t)(row0 + 16 + quad * 4 + r) * 256 + f] = f2bf(a1[r] + bs);
        }
      } else {
        ushort4 pk0, pk1;
        pk0.x = f2bf(a0[0] + bs); pk0.y = f2bf(a0[1] + bs);
        pk0.z = f2bf(a0[2] + bs); pk0.w = f2bf(a0[3] + bs);
        pk1.x = f2bf(a1[0] + bs); pk1.y = f2bf(a1[1] + bs);
        pk1.z = f2bf(a1[2] + bs); pk1.w = f2bf(a1[3] + bs);
        const int t0 = row0 + quad * 4;
        const int b0 = t0 >> 11, n0 = t0 & 2047;
        *(ushort4*)(vtb + (size_t)(b0 * 256 + f) * 2048 + n0) = pk0;
        const int t1 = t0 + 16;
        const int b1_ = t1 >> 11, n1 = t1 & 2047;
        *(ushort4*)(vtb + (size_t)(b1_ * 256 + f) * 2048 + n1) = pk1;
      }
    }
  }
}

// ---------------- kernel 3: flash attention ----------------
// M=32 q-rows/wave (2x 16-row frags): each K/V LDS fragment feeds 2 MFMAs
// (halves round-4's LDS-reads-per-MFMA, the measured bottleneck).
// Round-5 lessons baked in:
//  - NO register prefetch (32 loop-carried VGPRs -> spills: WRITE_SIZE 117MB).
//    Plain stage->barrier->compute, as in round 4 (which had clean 33MB writes).
//  - Vt stride 40 shorts (80B): b128 service-group (addr/16 mod 8 = col*5+quad)
//    is a bijection -> conflict-free (stride 32 gave 4-way conflicts).
//  - Pl stride 40: 16B-aligned b128 P-reads (stride 36 was only 8B-aligned).
// Kl stride 264: key*33+c mod 8 distinct within 8-lane group -> conflict-free.
// Fixed-offset softmax (exp(s*scale-8)); epilogue fully unrolled (rounds 1-2:
// dynamic O index -> scratch demotion).
// LDS 47.6 KB; grid (16,16) = 1 block/CU, 4 waves/CU.
__global__ __launch_bounds__(256, 1) void k_attn(
    const unsigned short* __restrict__ qb, const unsigned short* __restrict__ kb,
    const unsigned short* __restrict__ vtb, float* __restrict__ out) {
  __shared__ __align__(16) unsigned short Kl[32 * 264];    // [key][f]
  __shared__ __align__(16) unsigned short Vt[256 * 40];    // [f][key] pad 40
  __shared__ __align__(16) unsigned short Pl[4][32 * 40];  // [wave][row][key] pad 40
  const int tid = threadIdx.x;
  const int bx = blockIdx.x, b = blockIdx.y;
  const int w = tid >> 6, lane = tid & 63;
  const int col = lane & 15, quad = lane >> 4;
  const int n0 = bx * 128 + w * 32;
  const float scale = 0.0625f;  // 1/sqrt(256)

  // q A-frags for 2 row-tiles (64 VGPRs)
  bf16x8 qf0[8], qf1[8];
  const unsigned short* qrow0 = qb + (size_t)(b * 2048 + n0 + col) * 256 + quad * 8;
  const unsigned short* qrow1 = qrow0 + 16 * 256;
#pragma unroll
  for (int ks = 0; ks < 8; ++ks) {
    qf0[ks] = *(const bf16x8*)(qrow0 + ks * 32);
    qf1[ks] = *(const bf16x8*)(qrow1 + ks * 32);
  }

  f32x4 O0[16], O1[16];
#pragma unroll
  for (int ft = 0; ft < 16; ++ft) {
    O0[ft] = (f32x4){0.f, 0.f, 0.f, 0.f};
    O1[ft] = (f32x4){0.f, 0.f, 0.f, 0.f};
  }
  float ls0[4], ls1[4];
#pragma unroll
  for (int r = 0; r < 4; ++r) { ls0[r] = 0.f; ls1[r] = 0.f; }

  const uint4* ksrc = (const uint4*)(kb) + (size_t)b * 2048 * 32;  // [row][c:32]
  const uint4* vsrc = (const uint4*)(vtb);  // [(b*256+f)*256 + kt*4 + cc]
  unsigned short* Pw = Pl[w];

  for (int kt = 0; kt < 64; ++kt) {
    __syncthreads();  // all waves done reading K/V LDS of prev iter
    {  // stage K tile [32][256] and V^T tile [256][32] (transient registers)
#pragma unroll
      for (int pp = 0; pp < 4; ++pp) {
        const int idx = pp * 256 + tid;
        const int r = idx >> 5, c = idx & 31;
        *(uint4*)(Kl + r * 264 + c * 8) = ksrc[(size_t)(kt * 32 + r) * 32 + c];
        const int f = idx >> 2, cc = idx & 3;
        *(uint4*)(Vt + f * 40 + cc * 8) =
            vsrc[(size_t)(b * 256 + f) * 256 + kt * 4 + cc];
      }
    }
    __syncthreads();  // LDS tile ready
    // S = q @ k^T : 2 row-frags x 2 key-tiles; K-frags shared across row-frags
    f32x4 s00 = {0.f, 0.f, 0.f, 0.f}, s01 = {0.f, 0.f, 0.f, 0.f};
    f32x4 s10 = {0.f, 0.f, 0.f, 0.f}, s11 = {0.f, 0.f, 0.f, 0.f};
#pragma unroll
    for (int ks = 0; ks < 8; ++ks) {
      bf16x8 k0 = *(const bf16x8*)(Kl + col * 264 + ks * 32 + quad * 8);
      bf16x8 k1 = *(const bf16x8*)(Kl + (16 + col) * 264 + ks * 32 + quad * 8);
      s00 = __builtin_amdgcn_mfma_f32_16x16x32_bf16(qf0[ks], k0, s00, 0, 0, 0);
      s01 = __builtin_amdgcn_mfma_f32_16x16x32_bf16(qf0[ks], k1, s01, 0, 0, 0);
      s10 = __builtin_amdgcn_mfma_f32_16x16x32_bf16(qf1[ks], k0, s10, 0, 0, 0);
      s11 = __builtin_amdgcn_mfma_f32_16x16x32_bf16(qf1[ks], k1, s11, 0, 0, 0);
    }
    // fixed-offset exp; lane-local l accumulation; P -> per-wave LDS
#pragma unroll
    for (int r = 0; r < 4; ++r) {
      float p0 = __expf(fmaf(s00[r], scale, -8.0f));
      float p1 = __expf(fmaf(s01[r], scale, -8.0f));
      ls0[r] += p0 + p1;
      Pw[(quad * 4 + r) * 40 + col] = f2bf(p0);
      Pw[(quad * 4 + r) * 40 + 16 + col] = f2bf(p1);
      float q0 = __expf(fmaf(s10[r], scale, -8.0f));
      float q1 = __expf(fmaf(s11[r], scale, -8.0f));
      ls1[r] += q0 + q1;
      Pw[(16 + quad * 4 + r) * 40 + col] = f2bf(q0);
      Pw[(16 + quad * 4 + r) * 40 + 16 + col] = f2bf(q1);
    }
    // NO barrier: Pl[w] is per-wave; same-wave LDS RAW ordered by lgkmcnt.
    bf16x8 pf0 = *(const bf16x8*)(Pw + col * 40 + quad * 8);
    bf16x8 pf1 = *(const bf16x8*)(Pw + (16 + col) * 40 + quad * 8);
    // PV: O += P @ V ; V-frags shared across row-frags
#pragma unroll
    for (int ft = 0; ft < 16; ++ft) {
      bf16x8 vf = *(const bf16x8*)(Vt + (ft * 16 + col) * 40 + quad * 8);
      O0[ft] = __builtin_amdgcn_mfma_f32_16x16x32_bf16(pf0, vf, O0[ft], 0, 0, 0);
      O1[ft] = __builtin_amdgcn_mfma_f32_16x16x32_bf16(pf1, vf, O1[ft], 0, 0, 0);
    }
  }
  // epilogue: out = O / l  (FULLY UNROLLED — all O indices must be static)
  float rl0[4], rl1[4];
#pragma unroll
  for (int r = 0; r < 4; ++r) {
    rl0[r] = 1.0f / redsum16(ls0[r]);
    rl1[r] = 1.0f / redsum16(ls1[r]);
  }
#pragma unroll
  for (int ft = 0; ft < 16; ++ft) {
#pragma unroll
    for (int r = 0; r < 4; ++r) {
      const int n = n0 + quad * 4 + r;
      out[(size_t)(b * 2048 + n) * 256 + ft * 16 + col] = O0[ft][r] * rl0[r];
      out[(size_t)(b * 2048 + n + 16) * 256 + ft * 16 + col] = O1[ft][r] * rl1[r];
    }
  }
}

// ---------------- launcher ----------------
extern "C" void kernel_launch(void* const* d_in, const int* in_sizes, int n_in,
                              void* d_out, int out_size, void* d_ws, size_t ws_size,
                              hipStream_t stream) {
  const float* x  = (const float*)d_in[0];
  const float* p  = (const float*)d_in[1];
  const float* Wq = (const float*)d_in[2];
  const float* bq = (const float*)d_in[3];
  const float* Wk = (const float*)d_in[4];
  const float* bk = (const float*)d_in[5];
  const float* Wv = (const float*)d_in[6];
  const float* bv = (const float*)d_in[7];
  const float* W1 = (const float*)d_in[8];
  const float* b1 = (const float*)d_in[9];
  const float* W2 = (const float*)d_in[10];
  const float* b2 = (const float*)d_in[11];
  float* out = (float*)d_out;

  char* ws = (char*)d_ws;
  unsigned short* W2b = (unsigned short*)(ws + 0);
  unsigned short* Wqb = (unsigned short*)(ws + 131072);
  unsigned short* Wkb = (unsigned short*)(ws + 262144);
  unsigned short* Wvb = (unsigned short*)(ws + 393216);
  unsigned short* hb  = (unsigned short*)(ws + 524288);
  unsigned short* qb  = (unsigned short*)(ws + 524288 + 16777216);
  unsigned short* kb  = (unsigned short*)(ws + 524288 + 2 * 16777216);
  unsigned short* vtb = (unsigned short*)(ws + 524288 + 3 * 16777216);
  // total ws use: 524288 + 4*16777216 = 67,633,152 bytes

  k_wcvt<<<256, 256, 0, stream>>>(Wq, Wk, Wv, W2, Wqb, Wkb, Wvb, W2b);
  k_pos_h<<<512, 256, 0, stream>>>(x, p, W1, b1, W2b, b2, hb);
  k_qkv<<<256, 256, 0, stream>>>(hb, Wqb, bq, Wkb, bk, Wvb, bv, qb, kb, vtb);
  k_attn<<<dim3(16, 16), 256, 0, stream>>>(qb, kb, vtb, out);
}